// Round 7
// baseline (49.209 us; speedup 1.0000x reference)
//
#include <hip/hip_runtime.h>
#include <hip/hip_bf16.h>

#define N 1024
#define D 64

typedef __attribute__((ext_vector_type(8))) short bf16x8;
typedef __attribute__((ext_vector_type(16))) float f32x16;

__device__ __forceinline__ short f2bf(float x) {
    __hip_bfloat16 b = __float2bfloat16(x);
    return __builtin_bit_cast(short, b);
}

// ---------------------------------------------------------------------------
// K1: hi = X@w1a^T ; hjb = X@w1b^T + b1 ; trf = X@sig_w^T + sb.
// (exact round-4 kernel)
// ---------------------------------------------------------------------------
__global__ __launch_bounds__(256) void precompute_kernel(
    const float* __restrict__ cell, const float* __restrict__ w1,
    const float* __restrict__ b1, const float* __restrict__ sw,
    const float* __restrict__ sb,
    float* __restrict__ hi, float* __restrict__ hjb, float* __restrict__ trf)
{
    __shared__ float w1s[64 * 129];
    __shared__ float sws[64 * 65];
    __shared__ float xs[4 * 64];
    const int t = threadIdx.x;
    const int b = blockIdx.x;
    #pragma unroll
    for (int k = 0; k < 8; k++) {
        int f4 = t + 256 * k;
        int row = f4 >> 5, c4 = (f4 & 31) * 4;
        float4 v = *(const float4*)&w1[(size_t)row * 128 + c4];
        w1s[row * 129 + c4 + 0] = v.x;
        w1s[row * 129 + c4 + 1] = v.y;
        w1s[row * 129 + c4 + 2] = v.z;
        w1s[row * 129 + c4 + 3] = v.w;
    }
    #pragma unroll
    for (int k = 0; k < 4; k++) {
        int f4 = t + 256 * k;
        int row = f4 >> 4, c4 = (f4 & 15) * 4;
        float4 v = *(const float4*)&sw[(size_t)row * 64 + c4];
        sws[row * 65 + c4 + 0] = v.x;
        sws[row * 65 + c4 + 1] = v.y;
        sws[row * 65 + c4 + 2] = v.z;
        sws[row * 65 + c4 + 3] = v.w;
    }
    xs[t] = cell[(size_t)b * 256 + t];
    __syncthreads();
    const int wv = t >> 6, l = t & 63;
    const float* xr = &xs[wv * 64];
    float a0 = 0.0f, a1 = 0.0f, a2 = 0.0f;
    #pragma unroll 16
    for (int d = 0; d < 64; d++) {
        float x = xr[d];
        a0 = fmaf(x, w1s[l * 129 + d], a0);
        a1 = fmaf(x, w1s[l * 129 + 64 + d], a1);
        a2 = fmaf(x, sws[l * 65 + d], a2);
    }
    const int i = b * 4 + wv;
    hi[(size_t)i * D + l]  = a0;
    hjb[(size_t)i * D + l] = a1 + b1[l];
    trf[(size_t)i * D + l] = a2 + sb[l];
}

// ---------------------------------------------------------------------------
// K2: fused pairwise gate MLP + unnormalized weighted accumulation.
// (exact round-4 kernel: 4 waves, 32i x 64j, 16 jj/wave, grid (32,16))
// ---------------------------------------------------------------------------
__global__ __launch_bounds__(256, 3) void gate_fused_kernel(
    const float* __restrict__ A, const float* __restrict__ hi,
    const float* __restrict__ hjb, const float* __restrict__ trf,
    const float* __restrict__ w2, const float* __restrict__ b2,
    const float* __restrict__ w3, const float* __restrict__ b3,
    float* __restrict__ part, float* __restrict__ rsp)
{
    __shared__ float smem[8352];
    float* S1    = smem;           // [64 j][32 i]   A[j][i] side
    float* T2    = smem + 2048;    // [32 i][65]     A[i][j] side (padded)
    float* hjb_s = smem + 4128;    // [64 j][64 k]
    const int t   = threadIdx.x;
    const int w   = t >> 6;
    const int l   = t & 63;
    const int i0  = blockIdx.x * 32;
    const int by  = blockIdx.y;
    const int jb0 = by * 64;
    const int jbase = jb0 + w * 16;
    const int p   = l & 31;
    const int hi8 = l >> 5;
    const int i_mine = i0 + p;

    #pragma unroll
    for (int k = 0; k < 4; k++) {
        int f4 = t + 256 * k;
        *(float4*)&hjb_s[f4 * 4] = *(const float4*)&hjb[(size_t)jb0 * D + f4 * 4];
    }
    #pragma unroll
    for (int k = 0; k < 2; k++) {
        int f4 = t + 256 * k;
        int row = f4 >> 3, c4 = (f4 & 7) * 4;
        *(float4*)&S1[row * 32 + c4] =
            *(const float4*)&A[(size_t)(jb0 + row) * N + i0 + c4];
    }
    #pragma unroll
    for (int k = 0; k < 2; k++) {
        int f4 = t + 256 * k;
        int r = f4 >> 4, c4 = (f4 & 15) * 4;
        float4 v = *(const float4*)&A[(size_t)(i0 + r) * N + jb0 + c4];
        T2[r * 65 + c4 + 0] = v.x;
        T2[r * 65 + c4 + 1] = v.y;
        T2[r * 65 + c4 + 2] = v.z;
        T2[r * 65 + c4 + 3] = v.w;
    }

    float hv[32];
    #pragma unroll
    for (int q = 0; q < 4; q++) {
        float4 v0 = *(const float4*)&hi[(size_t)i_mine * D + q * 16 + hi8 * 8];
        float4 v1 = *(const float4*)&hi[(size_t)i_mine * D + q * 16 + hi8 * 8 + 4];
        hv[q * 8 + 0] = v0.x; hv[q * 8 + 1] = v0.y;
        hv[q * 8 + 2] = v0.z; hv[q * 8 + 3] = v0.w;
        hv[q * 8 + 4] = v1.x; hv[q * 8 + 5] = v1.y;
        hv[q * 8 + 6] = v1.z; hv[q * 8 + 7] = v1.w;
    }
    bf16x8 wa[4];
    #pragma unroll
    for (int q = 0; q < 4; q++) {
        const float* wp = &w2[(size_t)p * D + q * 16 + hi8 * 8];
        #pragma unroll
        for (int e = 0; e < 8; e++) wa[q][e] = f2bf(wp[e]);
    }
    float b2r[16], w3r[16];
    #pragma unroll
    for (int r = 0; r < 16; r++) {
        int ch = (r & 3) + 8 * (r >> 2) + 4 * hi8;
        b2r[r] = b2[ch];
        w3r[r] = w3[ch];
    }
    const float b3v = b3[0];

    __syncthreads();

    bf16x8 wf = {0, 0, 0, 0, 0, 0, 0, 0};
    float es = 0.0f;
    #pragma unroll
    for (int jj = 0; jj < 16; jj++) {
        const int jl = w * 16 + jj;
        const int j  = jb0 + jl;
        bf16x8 bq[4];
        #pragma unroll
        for (int q = 0; q < 4; q++) {
            float4 h0 = *(const float4*)&hjb_s[jl * 64 + q * 16 + hi8 * 8];
            float4 h1 = *(const float4*)&hjb_s[jl * 64 + q * 16 + hi8 * 8 + 4];
            bq[q][0] = f2bf(fmaxf(hv[q * 8 + 0] + h0.x, 0.0f));
            bq[q][1] = f2bf(fmaxf(hv[q * 8 + 1] + h0.y, 0.0f));
            bq[q][2] = f2bf(fmaxf(hv[q * 8 + 2] + h0.z, 0.0f));
            bq[q][3] = f2bf(fmaxf(hv[q * 8 + 3] + h0.w, 0.0f));
            bq[q][4] = f2bf(fmaxf(hv[q * 8 + 4] + h1.x, 0.0f));
            bq[q][5] = f2bf(fmaxf(hv[q * 8 + 5] + h1.y, 0.0f));
            bq[q][6] = f2bf(fmaxf(hv[q * 8 + 6] + h1.z, 0.0f));
            bq[q][7] = f2bf(fmaxf(hv[q * 8 + 7] + h1.w, 0.0f));
        }
        f32x16 accA, accB;
        #pragma unroll
        for (int r = 0; r < 16; r++) { accA[r] = b2r[r]; accB[r] = 0.0f; }
        accA = __builtin_amdgcn_mfma_f32_32x32x16_bf16(wa[0], bq[0], accA, 0, 0, 0);
        accA = __builtin_amdgcn_mfma_f32_32x32x16_bf16(wa[1], bq[1], accA, 0, 0, 0);
        accB = __builtin_amdgcn_mfma_f32_32x32x16_bf16(wa[2], bq[2], accB, 0, 0, 0);
        accB = __builtin_amdgcn_mfma_f32_32x32x16_bf16(wa[3], bq[3], accB, 0, 0, 0);

        float gp = 0.0f;
        #pragma unroll
        for (int r = 0; r < 16; r++)
            gp = fmaf(fmaxf(accA[r] + accB[r], 0.0f), w3r[r], gp);
        gp += __shfl_xor(gp, 32);

        const bool isdiag = (i_mine == j);
        float sym  = 0.5f * (S1[jl * 32 + p] + T2[p * 65 + jl]);
        float e    = isdiag ? 1.0f : __expf(sym);
        float gate = 1.0f / (1.0f + __expf(-(gp + b3v)));
        float u    = isdiag ? 0.0f : gate * e;
        if ((jj >> 3) == hi8) es += e;
        short ub = f2bf(u);
        wf[jj & 7] = ((jj >> 3) == hi8) ? ub : wf[jj & 7];
    }
    es += __shfl_xor(es, 32);

    bf16x8 tf0, tf1;
    #pragma unroll
    for (int e8 = 0; e8 < 8; e8++) {
        const float* tp = &trf[(size_t)(jbase + hi8 * 8 + e8) * D];
        tf0[e8] = f2bf(tp[p]);
        tf1[e8] = f2bf(tp[32 + p]);
    }
    f32x16 oA, oB;
    #pragma unroll
    for (int r = 0; r < 16; r++) { oA[r] = 0.0f; oB[r] = 0.0f; }
    oA = __builtin_amdgcn_mfma_f32_32x32x16_bf16(wf, tf0, oA, 0, 0, 0);
    oB = __builtin_amdgcn_mfma_f32_32x32x16_bf16(wf, tf1, oB, 0, 0, 0);

    __syncthreads();
    float* red = smem;
    float* esb = smem + 8192;
    #pragma unroll
    for (int r = 0; r < 16; r++) {
        int row = (r & 3) + 8 * (r >> 2) + 4 * hi8;
        red[w * 2048 + row * 64 + p]      = oA[r];
        red[w * 2048 + row * 64 + 32 + p] = oB[r];
    }
    if (hi8 == 0) esb[w * 32 + p] = es;
    __syncthreads();
    #pragma unroll
    for (int e = 0; e < 8; e++) {
        int idx = t + e * 256;
        float s = red[idx] + red[2048 + idx] + red[4096 + idx] + red[6144 + idx];
        part[(size_t)by * (N * D) + (size_t)i0 * D + idx] = s;
    }
    if (t < 32)
        rsp[by * N + i0 + t] = esb[t] + esb[32 + t] + esb[64 + t] + esb[96 + t];
}

// ---------------------------------------------------------------------------
// K3: out = cell + (sum_by part) / (sum_by rsp). (exact round-4 kernel)
// ---------------------------------------------------------------------------
__global__ __launch_bounds__(256) void finish_kernel(
    const float* __restrict__ cell, const float* __restrict__ part,
    const float* __restrict__ rsp, float* __restrict__ out)
{
    const int idx = blockIdx.x * 256 + threadIdx.x;
    const int i = idx >> 6;
    float rs = 0.0f;
    #pragma unroll
    for (int k = 0; k < 16; k++) rs += rsp[k * N + i];
    float acc = 0.0f;
    #pragma unroll
    for (int k = 0; k < 16; k++) acc += part[(size_t)k * (N * D) + idx];
    out[idx] = cell[idx] + acc / rs;
}

// ---------------------------------------------------------------------------
// MEASUREMENT ROUND: gate_fused_kernel launched TWICE (idempotent overwrite,
// deterministic). dur_us - 31.7 = steady-state gate duration.
// ---------------------------------------------------------------------------
extern "C" void kernel_launch(void* const* d_in, const int* in_sizes, int n_in,
                              void* d_out, int out_size, void* d_ws, size_t ws_size,
                              hipStream_t stream) {
    const float* cell = (const float*)d_in[0];
    const float* adj  = (const float*)d_in[1];
    const float* w1   = (const float*)d_in[2];
    const float* b1   = (const float*)d_in[3];
    const float* w2   = (const float*)d_in[4];
    const float* b2   = (const float*)d_in[5];
    const float* w3   = (const float*)d_in[6];
    const float* b3   = (const float*)d_in[7];
    const float* sw   = (const float*)d_in[8];
    const float* sb   = (const float*)d_in[9];
    float* out = (float*)d_out;

    float* ws    = (float*)d_ws;
    float* hi    = ws;                        // 64K
    float* hjb   = hi + N * D;                // 64K
    float* trf   = hjb + N * D;               // 64K
    float* part  = trf + N * D;               // 1M (16 x 64K)
    float* rsp   = part + (size_t)N * D * 16; // 16K

    precompute_kernel<<<256, 256, 0, stream>>>(cell, w1, b1, sw, sb, hi, hjb, trf);
    gate_fused_kernel<<<dim3(32, 16), 256, 0, stream>>>(adj, hi, hjb, trf,
                                                        w2, b2, w3, b3,
                                                        part, rsp);
    gate_fused_kernel<<<dim3(32, 16), 256, 0, stream>>>(adj, hi, hjb, trf,
                                                        w2, b2, w3, b3,
                                                        part, rsp);
    finish_kernel<<<256, 256, 0, stream>>>(cell, part, rsp, out);
}

// Round 8
// 31.948 us; speedup vs baseline: 1.5403x; 1.5403x over previous
//
#include <hip/hip_runtime.h>
#include <hip/hip_bf16.h>

#define N 1024
#define D 64

typedef __attribute__((ext_vector_type(8))) short bf16x8;
typedef __attribute__((ext_vector_type(16))) float f32x16;
typedef __attribute__((ext_vector_type(4))) float f32x4;

__device__ __forceinline__ short f2bf(float x) {
    __hip_bfloat16 b = __float2bfloat16(x);
    return __builtin_bit_cast(short, b);
}

// ---------------------------------------------------------------------------
// K1: hi = X@w1a^T ; hjb = X@w1b^T + b1 ; trf = X@sig_w^T + sb.
// (exact round-4 kernel)
// ---------------------------------------------------------------------------
__global__ __launch_bounds__(256) void precompute_kernel(
    const float* __restrict__ cell, const float* __restrict__ w1,
    const float* __restrict__ b1, const float* __restrict__ sw,
    const float* __restrict__ sb,
    float* __restrict__ hi, float* __restrict__ hjb, float* __restrict__ trf)
{
    __shared__ float w1s[64 * 129];
    __shared__ float sws[64 * 65];
    __shared__ float xs[4 * 64];
    const int t = threadIdx.x;
    const int b = blockIdx.x;
    #pragma unroll
    for (int k = 0; k < 8; k++) {
        int f4 = t + 256 * k;
        int row = f4 >> 5, c4 = (f4 & 31) * 4;
        float4 v = *(const float4*)&w1[(size_t)row * 128 + c4];
        w1s[row * 129 + c4 + 0] = v.x;
        w1s[row * 129 + c4 + 1] = v.y;
        w1s[row * 129 + c4 + 2] = v.z;
        w1s[row * 129 + c4 + 3] = v.w;
    }
    #pragma unroll
    for (int k = 0; k < 4; k++) {
        int f4 = t + 256 * k;
        int row = f4 >> 4, c4 = (f4 & 15) * 4;
        float4 v = *(const float4*)&sw[(size_t)row * 64 + c4];
        sws[row * 65 + c4 + 0] = v.x;
        sws[row * 65 + c4 + 1] = v.y;
        sws[row * 65 + c4 + 2] = v.z;
        sws[row * 65 + c4 + 3] = v.w;
    }
    xs[t] = cell[(size_t)b * 256 + t];
    __syncthreads();
    const int wv = t >> 6, l = t & 63;
    const float* xr = &xs[wv * 64];
    float a0 = 0.0f, a1 = 0.0f, a2 = 0.0f;
    #pragma unroll 16
    for (int d = 0; d < 64; d++) {
        float x = xr[d];
        a0 = fmaf(x, w1s[l * 129 + d], a0);
        a1 = fmaf(x, w1s[l * 129 + 64 + d], a1);
        a2 = fmaf(x, sws[l * 65 + d], a2);
    }
    const int i = b * 4 + wv;
    hi[(size_t)i * D + l]  = a0;
    hjb[(size_t)i * D + l] = a1 + b1[l];
    trf[(size_t)i * D + l] = a2 + sb[l];
}

// ---------------------------------------------------------------------------
// K2: fused pairwise gate MLP + unnormalized weighted accumulation.
// Round-4 skeleton (4 waves, 32i x 64j, 16 jj/wave, grid (32,16)) with
// inner-loop instruction cuts:
//  - b2 folded via MFMA C-operand; single 4-MFMA chain (no per-jj acc init)
//  - h1 build as packed f32x4 add/max
//  - vectorized b2/w3 loads
// ---------------------------------------------------------------------------
__global__ __launch_bounds__(256, 3) void gate_fused_kernel(
    const float* __restrict__ A, const float* __restrict__ hi,
    const float* __restrict__ hjb, const float* __restrict__ trf,
    const float* __restrict__ w2, const float* __restrict__ b2,
    const float* __restrict__ w3, const float* __restrict__ b3,
    float* __restrict__ part, float* __restrict__ rsp)
{
    __shared__ float smem[8352];
    float* S1    = smem;           // [64 j][32 i]   A[j][i] side
    float* T2    = smem + 2048;    // [32 i][65]     A[i][j] side (padded)
    float* hjb_s = smem + 4128;    // [64 j][64 k]
    const int t   = threadIdx.x;
    const int w   = t >> 6;
    const int l   = t & 63;
    const int i0  = blockIdx.x * 32;
    const int by  = blockIdx.y;
    const int jb0 = by * 64;
    const int jbase = jb0 + w * 16;
    const int p   = l & 31;
    const int hi8 = l >> 5;
    const int i_mine = i0 + p;

    #pragma unroll
    for (int k = 0; k < 4; k++) {
        int f4 = t + 256 * k;
        *(float4*)&hjb_s[f4 * 4] = *(const float4*)&hjb[(size_t)jb0 * D + f4 * 4];
    }
    #pragma unroll
    for (int k = 0; k < 2; k++) {
        int f4 = t + 256 * k;
        int row = f4 >> 3, c4 = (f4 & 7) * 4;
        *(float4*)&S1[row * 32 + c4] =
            *(const float4*)&A[(size_t)(jb0 + row) * N + i0 + c4];
    }
    #pragma unroll
    for (int k = 0; k < 2; k++) {
        int f4 = t + 256 * k;
        int r = f4 >> 4, c4 = (f4 & 15) * 4;
        float4 v = *(const float4*)&A[(size_t)(i0 + r) * N + jb0 + c4];
        T2[r * 65 + c4 + 0] = v.x;
        T2[r * 65 + c4 + 1] = v.y;
        T2[r * 65 + c4 + 2] = v.z;
        T2[r * 65 + c4 + 3] = v.w;
    }

    // hv as packed f32x4 (8 quads = lane's 32 k-values of hi)
    f32x4 hv4[8];
    #pragma unroll
    for (int q = 0; q < 4; q++) {
        hv4[2 * q]     = *(const f32x4*)&hi[(size_t)i_mine * D + q * 16 + hi8 * 8];
        hv4[2 * q + 1] = *(const f32x4*)&hi[(size_t)i_mine * D + q * 16 + hi8 * 8 + 4];
    }
    bf16x8 wa[4];
    #pragma unroll
    for (int q = 0; q < 4; q++) {
        const float* wp = &w2[(size_t)p * D + q * 16 + hi8 * 8];
        #pragma unroll
        for (int e = 0; e < 8; e++) wa[q][e] = f2bf(wp[e]);
    }
    // b2acc (MFMA C-operand) and w3r via vector loads:
    // reg r holds channel ch = (r&3) + 8*(r>>2) + 4*hi8  ->  b2[g*8+hi8*4+m]
    f32x16 b2acc;
    float w3r[16];
    #pragma unroll
    for (int g = 0; g < 4; g++) {
        f32x4 qb = *(const f32x4*)&b2[g * 8 + hi8 * 4];
        f32x4 qw = *(const f32x4*)&w3[g * 8 + hi8 * 4];
        #pragma unroll
        for (int m = 0; m < 4; m++) {
            b2acc[4 * g + m] = qb[m];
            w3r[4 * g + m]   = qw[m];
        }
    }
    const float b3v = b3[0];

    __syncthreads();

    const f32x4 z4 = {0.0f, 0.0f, 0.0f, 0.0f};
    bf16x8 wf = {0, 0, 0, 0, 0, 0, 0, 0};
    float es = 0.0f;
    #pragma unroll
    for (int jj = 0; jj < 16; jj++) {
        const int jl = w * 16 + jj;
        const int j  = jb0 + jl;
        bf16x8 bq[4];
        #pragma unroll
        for (int q = 0; q < 4; q++) {
            f32x4 a0 = hv4[2 * q] +
                       *(const f32x4*)&hjb_s[jl * 64 + q * 16 + hi8 * 8];
            f32x4 a1 = hv4[2 * q + 1] +
                       *(const f32x4*)&hjb_s[jl * 64 + q * 16 + hi8 * 8 + 4];
            a0 = __builtin_elementwise_max(a0, z4);
            a1 = __builtin_elementwise_max(a1, z4);
            bq[q][0] = f2bf(a0[0]); bq[q][1] = f2bf(a0[1]);
            bq[q][2] = f2bf(a0[2]); bq[q][3] = f2bf(a0[3]);
            bq[q][4] = f2bf(a1[0]); bq[q][5] = f2bf(a1[1]);
            bq[q][6] = f2bf(a1[2]); bq[q][7] = f2bf(a1[3]);
        }
        // single acc chain; b2 enters as the C operand of the first MFMA
        f32x16 acc;
        acc = __builtin_amdgcn_mfma_f32_32x32x16_bf16(wa[0], bq[0], b2acc, 0, 0, 0);
        acc = __builtin_amdgcn_mfma_f32_32x32x16_bf16(wa[1], bq[1], acc, 0, 0, 0);
        acc = __builtin_amdgcn_mfma_f32_32x32x16_bf16(wa[2], bq[2], acc, 0, 0, 0);
        acc = __builtin_amdgcn_mfma_f32_32x32x16_bf16(wa[3], bq[3], acc, 0, 0, 0);

        // gate_pre: two depth-8 max+fma chains
        float gp0 = 0.0f, gp1 = 0.0f;
        #pragma unroll
        for (int r = 0; r < 16; r += 2) {
            gp0 = fmaf(fmaxf(acc[r], 0.0f),     w3r[r],     gp0);
            gp1 = fmaf(fmaxf(acc[r + 1], 0.0f), w3r[r + 1], gp1);
        }
        float gp = gp0 + gp1;
        gp += __shfl_xor(gp, 32);

        const bool isdiag = (i_mine == j);
        float sym  = 0.5f * (S1[jl * 32 + p] + T2[p * 65 + jl]);
        float e    = isdiag ? 1.0f : __expf(sym);
        float gate = 1.0f / (1.0f + __expf(-(gp + b3v)));
        float u    = isdiag ? 0.0f : gate * e;
        if ((jj >> 3) == hi8) es += e;
        short ub = f2bf(u);
        wf[jj & 7] = ((jj >> 3) == hi8) ? ub : wf[jj & 7];
    }
    es += __shfl_xor(es, 32);

    bf16x8 tf0, tf1;
    #pragma unroll
    for (int e8 = 0; e8 < 8; e8++) {
        const float* tp = &trf[(size_t)(jbase + hi8 * 8 + e8) * D];
        tf0[e8] = f2bf(tp[p]);
        tf1[e8] = f2bf(tp[32 + p]);
    }
    f32x16 oA, oB;
    #pragma unroll
    for (int r = 0; r < 16; r++) { oA[r] = 0.0f; oB[r] = 0.0f; }
    oA = __builtin_amdgcn_mfma_f32_32x32x16_bf16(wf, tf0, oA, 0, 0, 0);
    oB = __builtin_amdgcn_mfma_f32_32x32x16_bf16(wf, tf1, oB, 0, 0, 0);

    __syncthreads();
    float* red = smem;
    float* esb = smem + 8192;
    #pragma unroll
    for (int r = 0; r < 16; r++) {
        int row = (r & 3) + 8 * (r >> 2) + 4 * hi8;
        red[w * 2048 + row * 64 + p]      = oA[r];
        red[w * 2048 + row * 64 + 32 + p] = oB[r];
    }
    if (hi8 == 0) esb[w * 32 + p] = es;
    __syncthreads();
    #pragma unroll
    for (int e = 0; e < 8; e++) {
        int idx = t + e * 256;
        float s = red[idx] + red[2048 + idx] + red[4096 + idx] + red[6144 + idx];
        part[(size_t)by * (N * D) + (size_t)i0 * D + idx] = s;
    }
    if (t < 32)
        rsp[by * N + i0 + t] = esb[t] + esb[32 + t] + esb[64 + t] + esb[96 + t];
}

// ---------------------------------------------------------------------------
// K3: out = cell + (sum_by part) / (sum_by rsp). (exact round-4 kernel)
// ---------------------------------------------------------------------------
__global__ __launch_bounds__(256) void finish_kernel(
    const float* __restrict__ cell, const float* __restrict__ part,
    const float* __restrict__ rsp, float* __restrict__ out)
{
    const int idx = blockIdx.x * 256 + threadIdx.x;
    const int i = idx >> 6;
    float rs = 0.0f;
    #pragma unroll
    for (int k = 0; k < 16; k++) rs += rsp[k * N + i];
    float acc = 0.0f;
    #pragma unroll
    for (int k = 0; k < 16; k++) acc += part[(size_t)k * (N * D) + idx];
    out[idx] = cell[idx] + acc / rs;
}

// ---------------------------------------------------------------------------
extern "C" void kernel_launch(void* const* d_in, const int* in_sizes, int n_in,
                              void* d_out, int out_size, void* d_ws, size_t ws_size,
                              hipStream_t stream) {
    const float* cell = (const float*)d_in[0];
    const float* adj  = (const float*)d_in[1];
    const float* w1   = (const float*)d_in[2];
    const float* b1   = (const float*)d_in[3];
    const float* w2   = (const float*)d_in[4];
    const float* b2   = (const float*)d_in[5];
    const float* w3   = (const float*)d_in[6];
    const float* b3   = (const float*)d_in[7];
    const float* sw   = (const float*)d_in[8];
    const float* sb   = (const float*)d_in[9];
    float* out = (float*)d_out;

    float* ws    = (float*)d_ws;
    float* hi    = ws;                        // 64K
    float* hjb   = hi + N * D;                // 64K
    float* trf   = hjb + N * D;               // 64K
    float* part  = trf + N * D;               // 1M (16 x 64K)
    float* rsp   = part + (size_t)N * D * 16; // 16K

    precompute_kernel<<<256, 256, 0, stream>>>(cell, w1, b1, sw, sb, hi, hjb, trf);
    gate_fused_kernel<<<dim3(32, 16), 256, 0, stream>>>(adj, hi, hjb, trf,
                                                        w2, b2, w3, b3,
                                                        part, rsp);
    finish_kernel<<<256, 256, 0, stream>>>(cell, part, rsp, out);
}